// Round 8
// baseline (559.553 us; speedup 1.0000x reference)
//
#include <hip/hip_runtime.h>
#include <stdint.h>

#define LN_EPS 1e-5f

// LayerNorm(C) + ReLU over a register array; g/b come from LDS (broadcast
// ds_read). Fully unrolled (reg arrays need compile-time indices).
template <int C>
__device__ __forceinline__ void ln_relu(float (&a)[C], const float* g,
                                        const float* b, float inv_c) {
  float p0 = 0.f, p1 = 0.f, p2 = 0.f, p3 = 0.f;
#pragma unroll
  for (int j = 0; j < C; j += 4) { p0 += a[j]; p1 += a[j + 1]; p2 += a[j + 2]; p3 += a[j + 3]; }
  float mu = ((p0 + p1) + (p2 + p3)) * inv_c;
  float q0 = 0.f, q1 = 0.f, q2 = 0.f, q3 = 0.f;
#pragma unroll
  for (int j = 0; j < C; j += 4) {
    float d0 = a[j] - mu, d1 = a[j + 1] - mu, d2 = a[j + 2] - mu, d3 = a[j + 3] - mu;
    a[j] = d0; a[j + 1] = d1; a[j + 2] = d2; a[j + 3] = d3;
    q0 = fmaf(d0, d0, q0); q1 = fmaf(d1, d1, q1); q2 = fmaf(d2, d2, q2); q3 = fmaf(d3, d3, q3);
  }
  float var = ((q0 + q1) + (q2 + q3)) * inv_c;
  float rs = rsqrtf(var + LN_EPS);
#pragma unroll
  for (int j = 0; j < C; ++j) {
    float t = a[j] * rs;
    t = fmaf(t, g[j], b[j]);
    a[j] = fmaxf(t, 0.f);
  }
}

// R8: R6 structure + ALL weights/LN-params staged in LDS, inner loops read
// them via wave-uniform ds_read_b128 (broadcast) instead of s_load.
// Evidence so far: x-prefetch +7% (R6), occupancy 4->8 waves 0% (R7), code
// size huge (R5). Stalls are correlated across waves => TLP can't cover
// them; the untested correlated stall is the scalar weight feed: per
// kk-step 32 FMAs (64 cyc issue) wait on s_load batches (K$ ~120-200 cyc,
// SGPR budget caps pipelining at 1-2 batches) => ~50% inner-loop efficiency,
// lockstep across waves. LDS broadcast reads issue from the DS category
// (co-issue with other waves' VALU), latency pipelined by compiler lgkmcnt.
// Staging: 10.8KB once per block, coalesced, barrier BEFORE the row guard
// (no divergent-return-before-barrier). Keeps R6 dist-1 x-prefetch.
// Predict: kernel ~145 -> ~95-115us (bench ~512 -> ~450-470); if neutral,
// weight path falsified -> pivot to bf16/MFMA.
__global__ __launch_bounds__(256) void dec_kernel(
    const float* __restrict__ x,
    const float* __restrict__ w1, const float* __restrict__ g1, const float* __restrict__ b1,
    const float* __restrict__ w2, const float* __restrict__ g2, const float* __restrict__ b2,
    const float* __restrict__ w3, const float* __restrict__ b3,
    float* __restrict__ out, int N, int HW)
{
  __shared__ __align__(16) float sw1[64 * 32];  // 8KB
  __shared__ __align__(16) float sw2[32 * 16];  // 2KB
  __shared__ __align__(16) float sw3[16 * 3];
  __shared__ __align__(16) float sg1[32], sb1[32];
  __shared__ __align__(16) float sg2[16], sb2[16];
  __shared__ float sb3[3];

  const int t = threadIdx.x;

  // ---- stage params (coalesced float4 where possible), one barrier ----
  {
    const float4* w1v = (const float4*)w1;
    float4*       s1v = (float4*)sw1;
#pragma unroll
    for (int i = 0; i < 2; ++i) s1v[t + i * 256] = w1v[t + i * 256];  // 512 f4
    if (t < 128) ((float4*)sw2)[t] = ((const float4*)w2)[t];          // 128 f4
    if (t < 48) sw3[t] = w3[t];
    if (t >= 64 && t < 96)   { sg1[t - 64] = g1[t - 64]; }
    if (t >= 96 && t < 128)  { sb1[t - 96] = b1[t - 96]; }
    if (t >= 128 && t < 144) { sg2[t - 128] = g2[t - 128]; }
    if (t >= 144 && t < 160) { sb2[t - 144] = b2[t - 144]; }
    if (t >= 160 && t < 163) { sb3[t - 160] = b3[t - 160]; }
  }
  __syncthreads();

  const int row = blockIdx.x * 256 + t;
  if (row < N) {
    const float4* __restrict__ xp = (const float4*)(x + (size_t)row * 64);

    // ---- layer 1: K=64 -> 32, rolled over 4 chunks, dist-1 x prefetch ----
    float acc[32];
#pragma unroll
    for (int j = 0; j < 32; ++j) acc[j] = 0.f;

    float4 c0 = xp[0], c1 = xp[1], c2 = xp[2], c3 = xp[3];

#pragma unroll 1
    for (int c = 0; c < 4; ++c) {
      const int nc = (c < 3) ? (c + 1) : 3;
      float4 n0 = xp[nc * 4 + 0];
      float4 n1 = xp[nc * 4 + 1];
      float4 n2 = xp[nc * 4 + 2];
      float4 n3 = xp[nc * 4 + 3];

#pragma unroll
      for (int q = 0; q < 4; ++q) {
        const float4 xq = (q == 0) ? c0 : (q == 1) ? c1 : (q == 2) ? c2 : c3;
#pragma unroll
        for (int kk = 0; kk < 4; ++kk) {
          const float xk = (kk == 0) ? xq.x : (kk == 1) ? xq.y : (kk == 2) ? xq.z : xq.w;
          // wave-uniform LDS address -> broadcast ds_read_b128 x8
          const float4* wrow = (const float4*)(sw1 + (c * 16 + q * 4 + kk) * 32);
#pragma unroll
          for (int jj = 0; jj < 8; ++jj) {
            const float4 wv = wrow[jj];
            acc[jj * 4 + 0] = fmaf(xk, wv.x, acc[jj * 4 + 0]);
            acc[jj * 4 + 1] = fmaf(xk, wv.y, acc[jj * 4 + 1]);
            acc[jj * 4 + 2] = fmaf(xk, wv.z, acc[jj * 4 + 2]);
            acc[jj * 4 + 3] = fmaf(xk, wv.w, acc[jj * 4 + 3]);
          }
        }
      }
      c0 = n0; c1 = n1; c2 = n2; c3 = n3;
    }

    ln_relu<32>(acc, sg1, sb1, 0.03125f);

    // ---- layer 2: K=32 -> 16 ----
    float a2[16];
#pragma unroll
    for (int j = 0; j < 16; ++j) a2[j] = 0.f;
#pragma unroll
    for (int k = 0; k < 32; ++k) {
      const float hk = acc[k];
      const float4* wrow = (const float4*)(sw2 + k * 16);  // uniform -> broadcast
#pragma unroll
      for (int jj = 0; jj < 4; ++jj) {
        const float4 wv = wrow[jj];
        a2[jj * 4 + 0] = fmaf(hk, wv.x, a2[jj * 4 + 0]);
        a2[jj * 4 + 1] = fmaf(hk, wv.y, a2[jj * 4 + 1]);
        a2[jj * 4 + 2] = fmaf(hk, wv.z, a2[jj * 4 + 2]);
        a2[jj * 4 + 3] = fmaf(hk, wv.w, a2[jj * 4 + 3]);
      }
    }

    ln_relu<16>(a2, sg2, sb2, 0.0625f);

    // ---- layer 3 + channel L2-normalize ----
    float o0 = sb3[0], o1 = sb3[1], o2 = sb3[2];
#pragma unroll
    for (int k = 0; k < 16; ++k) {
      const float hk = a2[k];
      o0 = fmaf(hk, sw3[k * 3 + 0], o0);
      o1 = fmaf(hk, sw3[k * 3 + 1], o1);
      o2 = fmaf(hk, sw3[k * 3 + 2], o2);
    }
    const float nsq = fmaf(o0, o0, fmaf(o1, o1, o2 * o2));
    const float inv = rsqrtf(fmaxf(nsq, 1e-24f));  // == 1/max(||o||,1e-12)
    o0 *= inv; o1 *= inv; o2 *= inv;

    // out[b][c][h][w]; flat = b*3*HW + c*HW + p; lanes consecutive in p
    const unsigned bb = (unsigned)row / (unsigned)HW;
    const unsigned p  = (unsigned)row - bb * (unsigned)HW;
    const size_t obase = (size_t)bb * 3 * HW + p;
    out[obase]          = o0;
    out[obase + HW]     = o1;
    out[obase + 2 * HW] = o2;
  }
}

extern "C" void kernel_launch(void* const* d_in, const int* in_sizes, int n_in,
                              void* d_out, int out_size, void* d_ws, size_t ws_size,
                              hipStream_t stream) {
  const float* x  = (const float*)d_in[0];
  const float* w1 = (const float*)d_in[1];
  const float* g1 = (const float*)d_in[2];
  const float* b1 = (const float*)d_in[3];
  const float* w2 = (const float*)d_in[4];
  const float* g2 = (const float*)d_in[5];
  const float* b2 = (const float*)d_in[6];
  const float* w3 = (const float*)d_in[7];
  const float* b3 = (const float*)d_in[8];
  float* out = (float*)d_out;

  const int N  = in_sizes[0] / 64;  // rows
  const int HW = N / 4;             // B = 4 per reference setup
  const int nblocks = (N + 255) / 256;
  dec_kernel<<<nblocks, 256, 0, stream>>>(x, w1, g1, b1, w2, g2, b2, w3, b3, out, N, HW);
}